// Round 6
// baseline (854.373 us; speedup 1.0000x reference)
//
#include <hip/hip_runtime.h>
#include <hip/hip_cooperative_groups.h>
#include <math.h>

namespace cg = cooperative_groups;

#define SCALE 0.1020620726159658f  // 96^-0.5

typedef __attribute__((ext_vector_type(8))) short shortx8;
typedef __attribute__((ext_vector_type(4))) float floatx4;

__device__ __forceinline__ unsigned short f2bf(float f) {
  union { float f; unsigned int i; } c; c.f = f;
  unsigned int x = c.i;
  x += 0x7fffu + ((x >> 16) & 1u);
  return (unsigned short)(x >> 16);
}
// tanh-form gelu via native exp2 (validated rounds 3-4: absmax 0.0039)
__device__ __forceinline__ float gelu_fast(float x) {
  float x2 = x * x;
  float y = x * (0.7978845608f + 0.0356774081f * x2);
  float e = fminf(y * 2.885390082f, 60.0f);
  float t = exp2f(e);
  return x * t * __builtin_amdgcn_rcpf(t + 1.0f);
}
__device__ __forceinline__ void async_ld16(const unsigned short* g, unsigned short* l) {
  __builtin_amdgcn_global_load_lds(
      (const __attribute__((address_space(1))) unsigned int*)g,
      (__attribute__((address_space(3))) unsigned int*)l, 16, 0, 0);
}
// 8 fp32 -> 8 bf16, store 16B
__device__ __forceinline__ void cvt_store8(const float* __restrict__ src,
                                           unsigned short* __restrict__ dst) {
  float4 a = *(const float4*)src;
  float4 b = *(const float4*)(src + 4);
  shortx8 v;
  v[0] = (short)f2bf(a.x); v[1] = (short)f2bf(a.y);
  v[2] = (short)f2bf(a.z); v[3] = (short)f2bf(a.w);
  v[4] = (short)f2bf(b.x); v[5] = (short)f2bf(b.y);
  v[6] = (short)f2bf(b.z); v[7] = (short)f2bf(b.w);
  *(shortx8*)dst = v;
}
// MFMA consume of one 128x128x64 LDS tile (16x16x32 bf16, 4 waves, 64x64/wave)
__device__ __forceinline__ void mfma_consume(const unsigned short* __restrict__ As,
                                             const unsigned short* __restrict__ Bs,
                                             int wr, int wc, int quad, int l15,
                                             floatx4 (&acc)[4][4]) {
#pragma unroll
  for (int ks = 0; ks < 2; ks++) {
    shortx8 af[4], bfr[4];
#pragma unroll
    for (int mt = 0; mt < 4; mt++) {
      int r = wr * 64 + mt * 16 + l15;
      int ch = (ks * 4 + quad) ^ (r & 7);
      af[mt] = *(const shortx8*)(As + r * 64 + ch * 8);
    }
#pragma unroll
    for (int nt = 0; nt < 4; nt++) {
      int r = wc * 64 + nt * 16 + l15;
      int ch = (ks * 4 + quad) ^ (r & 7);
      bfr[nt] = *(const shortx8*)(Bs + r * 64 + ch * 8);
    }
#pragma unroll
    for (int mt = 0; mt < 4; mt++)
#pragma unroll
      for (int nt = 0; nt < 4; nt++)
        acc[mt][nt] = __builtin_amdgcn_mfma_f32_16x16x32_bf16(
            af[mt], bfr[nt], acc[mt][nt], 0, 0, 0);
  }
}

// ---------------- Phase A: search fp32->bf16 + Wk transpose ----------------
__device__ void phaseA(const float* __restrict__ search, const float* __restrict__ Wk,
                       unsigned short* __restrict__ WkT, unsigned short* __restrict__ sb,
                       int use_sb, unsigned short* __restrict__ tilebuf) {
  const int t = threadIdx.x;
  const int total = use_sb ? 6720 : 576;
  for (int it = blockIdx.x; it < total; it += gridDim.x) {
    int tr = use_sb ? (it - 6144) : it;
    if (use_sb && it < 6144) {
      size_t i = (size_t)it * 2048 + t * 8;
      cvt_store8(search + i, sb + i);
    } else {
      unsigned short(*tile)[33] = (unsigned short(*)[33])tilebuf;
      int bx = tr % 24, by = tr / 24;
      int tx = t & 31, ty = t >> 5;
      __syncthreads();
#pragma unroll
      for (int i = 0; i < 4; i++)
        tile[ty + i * 8][tx] = f2bf(Wk[(size_t)(by * 32 + ty + i * 8) * 768 + bx * 32 + tx]);
      __syncthreads();
#pragma unroll
      for (int i = 0; i < 4; i++)
        WkT[(size_t)(bx * 32 + ty + i * 8) * 768 + by * 32 + tx] = tile[tx][ty + i * 8];
    }
  }
}

// ---------------- Phase B: q-proj (64x64 tiles, 48 blocks) ----------------
// qv = (query @ Wq^T + bq); qf fp32; QW[(row*4+j),col] = bf16(SCALE*W1[j,col/96]*qv)
__device__ void phaseB(const float* __restrict__ query, const float* __restrict__ Wq,
                       const float* __restrict__ bq, const float* __restrict__ W1,
                       float* __restrict__ qf, unsigned short* __restrict__ QW,
                       unsigned short* __restrict__ As, unsigned short* __restrict__ Bs) {
  const int bid = blockIdx.x;
  if (bid >= 48) return;
  const int t = threadIdx.x, wave = t >> 6, lane = t & 63;
  const int by = bid / 12, bx = bid % 12;
  const int m0 = by * 64, n0 = bx * 64;
  const int wr = wave >> 1, wc = wave & 1;
  const int quad = lane >> 4, l15 = lane & 15;
  const int rl = lane >> 3, cL = lane & 7, p = cL ^ rl;
  floatx4 acc[2][2];
#pragma unroll
  for (int i = 0; i < 2; i++)
#pragma unroll
    for (int j = 0; j < 2; j++) acc[i][j] = (floatx4){0.f, 0.f, 0.f, 0.f};
  for (int k0 = 0; k0 < 768; k0 += 64) {
#pragma unroll
    for (int tt = 0; tt < 2; tt++) {
      int r = wave * 16 + tt * 8 + rl;
      cvt_store8(query + (size_t)(m0 + r) * 768 + k0 + cL * 8, As + r * 64 + p * 8);
      cvt_store8(Wq + (size_t)(n0 + r) * 768 + k0 + cL * 8, Bs + r * 64 + p * 8);
    }
    __syncthreads();
#pragma unroll
    for (int ks = 0; ks < 2; ks++) {
      shortx8 af[2], bfr[2];
#pragma unroll
      for (int mt = 0; mt < 2; mt++) {
        int r = wr * 32 + mt * 16 + l15;
        int ch = (ks * 4 + quad) ^ (r & 7);
        af[mt] = *(const shortx8*)(As + r * 64 + ch * 8);
      }
#pragma unroll
      for (int nt = 0; nt < 2; nt++) {
        int r = wc * 32 + nt * 16 + l15;
        int ch = (ks * 4 + quad) ^ (r & 7);
        bfr[nt] = *(const shortx8*)(Bs + r * 64 + ch * 8);
      }
#pragma unroll
      for (int mt = 0; mt < 2; mt++)
#pragma unroll
        for (int nt = 0; nt < 2; nt++)
          acc[mt][nt] = __builtin_amdgcn_mfma_f32_16x16x32_bf16(
              af[mt], bfr[nt], acc[mt][nt], 0, 0, 0);
    }
    __syncthreads();
  }
  const int lrow = quad * 4;
#pragma unroll
  for (int mt = 0; mt < 2; mt++)
#pragma unroll
    for (int nt = 0; nt < 2; nt++) {
      int gm = m0 + wr * 32 + mt * 16 + lrow;
      int gn = n0 + wc * 32 + nt * 16 + l15;
      float bz = bq[gn];
      int h = gn / 96;
      float w1h0 = W1[h], w1h1 = W1[8 + h], w1h2 = W1[16 + h], w1h3 = W1[24 + h];
#pragma unroll
      for (int r = 0; r < 4; r++) {
        float qv = acc[mt][nt][r] + bz;
        qf[(size_t)(gm + r) * 768 + gn] = qv;
        size_t base = (size_t)((gm + r) * 4) * 768 + gn;
        QW[base]           = f2bf(SCALE * w1h0 * qv);
        QW[base + 768]     = f2bf(SCALE * w1h1 * qv);
        QW[base + 2 * 768] = f2bf(SCALE * w1h2 * qv);
        QW[base + 3 * 768] = f2bf(SCALE * w1h3 * qv);
      }
    }
}

// ---------------- Phase C: QQ GEMM (48) + cp (4) + sb L2 prefetch (rest) ----
__device__ void phaseC(const unsigned short* __restrict__ QW,
                       const unsigned short* __restrict__ WkT,
                       unsigned short* __restrict__ QQ,
                       const float* __restrict__ qf, const float* __restrict__ W1,
                       const float* __restrict__ b1, const float* __restrict__ bk,
                       float* __restrict__ cp, const unsigned short* __restrict__ sb,
                       int use_sb, float* __restrict__ dummy,
                       unsigned short* __restrict__ As, unsigned short* __restrict__ Bs) {
  const int bid = blockIdx.x;
  const int t = threadIdx.x, wave = t >> 6, lane = t & 63;
  if (bid < 48) {
    const int by = bid / 6, bx = bid % 6;
    const int m0 = by * 128, n0 = bx * 128;
    const int wr = wave >> 1, wc = wave & 1;
    const int quad = lane >> 4, l15 = lane & 15;
    floatx4 acc[4][4];
#pragma unroll
    for (int i = 0; i < 4; i++)
#pragma unroll
      for (int j = 0; j < 4; j++) acc[i][j] = (floatx4){0.f, 0.f, 0.f, 0.f};
    const int rl = lane >> 3, cl = (lane & 7) ^ rl;
    for (int k0 = 0; k0 < 768; k0 += 64) {
#pragma unroll
      for (int tt = 0; tt < 4; tt++) {
        int rr = wave * 32 + tt * 8;
        async_ld16(QW + (size_t)(m0 + rr + rl) * 768 + k0 + cl * 8, As + rr * 64);
      }
#pragma unroll
      for (int tt = 0; tt < 4; tt++) {
        int rr = wave * 32 + tt * 8;
        async_ld16(WkT + (size_t)(n0 + rr + rl) * 768 + k0 + cl * 8, Bs + rr * 64);
      }
      __syncthreads();
      mfma_consume(As, Bs, wr, wc, quad, l15, acc);
      __syncthreads();
    }
    const int lrow = quad * 4;
#pragma unroll
    for (int mt = 0; mt < 4; mt++)
#pragma unroll
      for (int nt = 0; nt < 4; nt++) {
        int gm = m0 + wr * 64 + mt * 16 + lrow;
        int gn = n0 + wc * 64 + nt * 16 + l15;
#pragma unroll
        for (int r = 0; r < 4; r++)
          QQ[(size_t)(gm + r) * 768 + gn] = f2bf(acc[mt][nt][r]);
      }
  } else if (bid < 52) {
    // cp[b*4+j] = b1[j] + SCALE * sum_h W1[j,h] * dot(qf[b,h*96:],bk[h*96:])
    const int bstart = (bid - 48) * 64;
    for (int b = bstart + wave; b < bstart + 64; b += 4) {
      const float* qrow = qf + (size_t)b * 768;
      int e0 = lane * 12;
      float s = 0.f;
#pragma unroll
      for (int i = 0; i < 12; i++) s += qrow[e0 + i] * bk[e0 + i];
      s += __shfl_xor(s, 1); s += __shfl_xor(s, 2); s += __shfl_xor(s, 4);
      float v = __shfl(s, (lane & 7) * 8);
      float w = W1[((lane >> 3) & 3) * 8 + (lane & 7)] * v;
      w += __shfl_xor(w, 1); w += __shfl_xor(w, 2); w += __shfl_xor(w, 4);
      if (lane < 32 && (lane & 7) == 0) {
        int j = lane >> 3;
        cp[b * 4 + j] = b1[j] + SCALE * w;
      }
    }
  } else if (use_sb) {
    // warm this block's phase-D sb n-tile into the local XCD L2
    const int n_tile = (bid & 7) * 16 + ((bid >> 3) & 15);
    const float4* p4 = (const float4*)(sb + (size_t)n_tile * 128 * 768);
    float s = 0.f;
#pragma unroll 4
    for (int i = 0; i < 48; i++) {
      float4 v = p4[i * 256 + t];
      s += v.x + v.y + v.z + v.w;
    }
    if (s == 1.2345e-37f) *dummy = s;  // never true in practice; defeats DCE
  }
}

// ---------------- Phase D: main GEMM + fused MLP epilogue ----------------
__device__ void phaseD(const unsigned short* __restrict__ QQ, const void* __restrict__ Bv,
                       float* __restrict__ out, const float* __restrict__ cp,
                       const float* __restrict__ W2, const float* __restrict__ b2,
                       int use_sb,
                       unsigned short* __restrict__ As, unsigned short* __restrict__ Bs) {
  const int bid = blockIdx.x;
  const int n_tile = (bid & 7) * 16 + ((bid >> 3) & 15);
  const int m_tile = bid >> 7;
  const int m0 = m_tile * 128, n0 = n_tile * 128;
  const int t = threadIdx.x, wave = t >> 6, lane = t & 63;
  const int wr = wave >> 1, wc = wave & 1;
  const int quad = lane >> 4, l15 = lane & 15;
  floatx4 acc[4][4];
#pragma unroll
  for (int i = 0; i < 4; i++)
#pragma unroll
    for (int j = 0; j < 4; j++) acc[i][j] = (floatx4){0.f, 0.f, 0.f, 0.f};
  const int rl = lane >> 3, cl = (lane & 7) ^ rl, cL = lane & 7, p = cL ^ rl;
  for (int k0 = 0; k0 < 768; k0 += 64) {
#pragma unroll
    for (int tt = 0; tt < 4; tt++) {
      int rr = wave * 32 + tt * 8;
      async_ld16(QQ + (size_t)(m0 + rr + rl) * 768 + k0 + cl * 8, As + rr * 64);
    }
    if (use_sb) {
      const unsigned short* B16 = (const unsigned short*)Bv;
#pragma unroll
      for (int tt = 0; tt < 4; tt++) {
        int rr = wave * 32 + tt * 8;
        async_ld16(B16 + (size_t)(n0 + rr + rl) * 768 + k0 + cl * 8, Bs + rr * 64);
      }
    } else {
      const float* Bf = (const float*)Bv;
#pragma unroll
      for (int tt = 0; tt < 4; tt++) {
        int r = wave * 32 + tt * 8 + rl;
        cvt_store8(Bf + (size_t)(n0 + r) * 768 + k0 + cL * 8, Bs + r * 64 + p * 8);
      }
    }
    __syncthreads();
    mfma_consume(As, Bs, wr, wc, quad, l15, acc);
    __syncthreads();
  }
  const float w2v0 = W2[0], w2v1 = W2[1], w2v2 = W2[2], w2v3 = W2[3];
  const float b2v = b2[0];
  const int lrow = quad * 4;
#pragma unroll
  for (int mt = 0; mt < 4; mt++) {
    int gm = m0 + wr * 64 + mt * 16 + lrow;  // multiple of 4: rows gm..gm+3 = j 0..3
    float cpv0 = cp[gm], cpv1 = cp[gm + 1], cpv2 = cp[gm + 2], cpv3 = cp[gm + 3];
#pragma unroll
    for (int nt = 0; nt < 4; nt++) {
      int gn = n0 + wc * 64 + nt * 16 + l15;
      floatx4 v = acc[mt][nt];
      float s = b2v;
      s += w2v0 * gelu_fast(v[0] + cpv0);
      s += w2v1 * gelu_fast(v[1] + cpv1);
      s += w2v2 * gelu_fast(v[2] + cpv2);
      s += w2v3 * gelu_fast(v[3] + cpv3);
      out[(size_t)(gm >> 2) * 16384 + gn] = s;
    }
  }
}

// ---------------- Cooperative all-in-one ----------------
__global__ __launch_bounds__(256, 4) void fused_all(
    const float* query, const float* search, const float* Wq, const float* bq,
    const float* Wk, const float* bk, const float* W1, const float* b1,
    const float* W2, const float* b2, float* out,
    unsigned short* WkT, unsigned short* QW, float* qf,
    unsigned short* QQ, unsigned short* sb, float* cp, float* dummy, int use_sb)
{
  __shared__ unsigned short As[128 * 64];
  __shared__ unsigned short Bs[128 * 64];
  cg::grid_group grid = cg::this_grid();
  phaseA(search, Wk, WkT, sb, use_sb, As);
  __threadfence();
  grid.sync();
  phaseB(query, Wq, bq, W1, qf, QW, As, Bs);
  __threadfence();
  grid.sync();
  phaseC(QW, WkT, QQ, qf, W1, b1, bk, cp, sb, use_sb, dummy, As, Bs);
  __threadfence();
  grid.sync();
  phaseD(QQ, use_sb ? (const void*)sb : (const void*)search, out, cp, W2, b2,
         use_sb, As, Bs);
}

// ---------------- Fallback plain launches (no grid sync) ----------------
__global__ __launch_bounds__(256, 4) void kA(const float* search, const float* Wk,
                                             unsigned short* WkT, unsigned short* sb,
                                             int use_sb) {
  __shared__ unsigned short As[128 * 64];
  phaseA(search, Wk, WkT, sb, use_sb, As);
}
__global__ __launch_bounds__(256, 4) void kB(const float* query, const float* Wq,
                                             const float* bq, const float* W1,
                                             float* qf, unsigned short* QW) {
  __shared__ unsigned short As[128 * 64];
  __shared__ unsigned short Bs[128 * 64];
  phaseB(query, Wq, bq, W1, qf, QW, As, Bs);
}
__global__ __launch_bounds__(256, 4) void kC(const unsigned short* QW,
                                             const unsigned short* WkT,
                                             unsigned short* QQ, const float* qf,
                                             const float* W1, const float* b1,
                                             const float* bk, float* cp,
                                             const unsigned short* sb, int use_sb,
                                             float* dummy) {
  __shared__ unsigned short As[128 * 64];
  __shared__ unsigned short Bs[128 * 64];
  phaseC(QW, WkT, QQ, qf, W1, b1, bk, cp, sb, use_sb, dummy, As, Bs);
}
__global__ __launch_bounds__(256, 4) void kD(const unsigned short* QQ, const void* Bv,
                                             float* out, const float* cp,
                                             const float* W2, const float* b2,
                                             int use_sb) {
  __shared__ unsigned short As[128 * 64];
  __shared__ unsigned short Bs[128 * 64];
  phaseD(QQ, Bv, out, cp, W2, b2, use_sb, As, Bs);
}

extern "C" void kernel_launch(void* const* d_in, const int* in_sizes, int n_in,
                              void* d_out, int out_size, void* d_ws, size_t ws_size,
                              hipStream_t stream) {
  const float* query  = (const float*)d_in[0];
  const float* search = (const float*)d_in[1];
  const float* Wq     = (const float*)d_in[2];
  const float* bq     = (const float*)d_in[3];
  const float* Wk     = (const float*)d_in[4];
  const float* bk     = (const float*)d_in[5];
  const float* W1     = (const float*)d_in[6];
  const float* b1     = (const float*)d_in[7];
  const float* W2     = (const float*)d_in[8];
  const float* b2     = (const float*)d_in[9];
  float* out = (float*)d_out;

  char* ws = (char*)d_ws;
  float*          cp    = (float*)ws;                       //     4,096 B
  float*          dummy = (float*)(ws + 4096);              //        16 B
  float*          qf    = (float*)(ws + 4352);              //   786,432 B
  unsigned short* WkT   = (unsigned short*)(ws + 790784);   // 1,179,648 B
  unsigned short* QW    = (unsigned short*)(ws + 1970432);  // 1,572,864 B
  unsigned short* QQ    = (unsigned short*)(ws + 3543296);  // 1,572,864 B
  unsigned short* sb    = (unsigned short*)(ws + 5116160);  // 25,165,824 B -> 30,281,984
  int use_sb = (ws_size >= 30281984u) ? 1 : 0;

  void* kargs[] = {
      (void*)&query, (void*)&search, (void*)&Wq, (void*)&bq, (void*)&Wk,
      (void*)&bk, (void*)&W1, (void*)&b1, (void*)&W2, (void*)&b2,
      (void*)&out, (void*)&WkT, (void*)&QW, (void*)&qf, (void*)&QQ,
      (void*)&sb, (void*)&cp, (void*)&dummy, (void*)&use_sb};
  hipError_t err = hipLaunchCooperativeKernel((const void*)fused_all, dim3(1024),
                                              dim3(256), kargs, 0, stream);
  if (err != hipSuccess) {
    (void)hipGetLastError();
    kA<<<1024, 256, 0, stream>>>(search, Wk, WkT, sb, use_sb);
    kB<<<48, 256, 0, stream>>>(query, Wq, bq, W1, qf, QW);
    kC<<<52, 256, 0, stream>>>(QW, WkT, QQ, qf, W1, b1, bk, cp, sb, use_sb, dummy);
    kD<<<1024, 256, 0, stream>>>(QQ, use_sb ? (const void*)sb : (const void*)search,
                                 out, cp, W2, b2, use_sb);
  }
}

// Round 7
// 167.911 us; speedup vs baseline: 5.0882x; 5.0882x over previous
//
#include <hip/hip_runtime.h>
#include <math.h>

#define SCALE 0.1020620726159658f  // 96^-0.5

typedef __attribute__((ext_vector_type(8))) short shortx8;
typedef __attribute__((ext_vector_type(4))) float floatx4;

__device__ __forceinline__ unsigned short f2bf(float f) {
  union { float f; unsigned int i; } c; c.f = f;
  unsigned int x = c.i;
  x += 0x7fffu + ((x >> 16) & 1u);
  return (unsigned short)(x >> 16);
}
// tanh-form gelu via native exp2 (validated rounds 3-6: absmax 0.0039)
__device__ __forceinline__ float gelu_fast(float x) {
  float x2 = x * x;
  float y = x * (0.7978845608f + 0.0356774081f * x2);
  float e = fminf(y * 2.885390082f, 60.0f);
  float t = exp2f(e);
  return x * t * __builtin_amdgcn_rcpf(t + 1.0f);
}
__device__ __forceinline__ void async_ld16(const unsigned short* g, unsigned short* l) {
  __builtin_amdgcn_global_load_lds(
      (const __attribute__((address_space(1))) unsigned int*)g,
      (__attribute__((address_space(3))) unsigned int*)l, 16, 0, 0);
}
// 8 fp32 -> 8 bf16, store 16B
__device__ __forceinline__ void cvt_store8(const float* __restrict__ src,
                                           unsigned short* __restrict__ dst) {
  float4 a = *(const float4*)src;
  float4 b = *(const float4*)(src + 4);
  shortx8 v;
  v[0] = (short)f2bf(a.x); v[1] = (short)f2bf(a.y);
  v[2] = (short)f2bf(a.z); v[3] = (short)f2bf(a.w);
  v[4] = (short)f2bf(b.x); v[5] = (short)f2bf(b.y);
  v[6] = (short)f2bf(b.z); v[7] = (short)f2bf(b.w);
  *(shortx8*)dst = v;
}
// MFMA consume of one 128x128x64 LDS tile (16x16x32 bf16, 4 waves, 64x64/wave)
__device__ __forceinline__ void mfma_consume(const unsigned short* __restrict__ As,
                                             const unsigned short* __restrict__ Bs,
                                             int wr, int wc, int quad, int l15,
                                             floatx4 (&acc)[4][4]) {
#pragma unroll
  for (int ks = 0; ks < 2; ks++) {
    shortx8 af[4], bfr[4];
#pragma unroll
    for (int mt = 0; mt < 4; mt++) {
      int r = wr * 64 + mt * 16 + l15;
      int ch = (ks * 4 + quad) ^ (r & 7);
      af[mt] = *(const shortx8*)(As + r * 64 + ch * 8);
    }
#pragma unroll
    for (int nt = 0; nt < 4; nt++) {
      int r = wc * 64 + nt * 16 + l15;
      int ch = (ks * 4 + quad) ^ (r & 7);
      bfr[nt] = *(const shortx8*)(Bs + r * 64 + ch * 8);
    }
#pragma unroll
    for (int mt = 0; mt < 4; mt++)
#pragma unroll
      for (int nt = 0; nt < 4; nt++)
        acc[mt][nt] = __builtin_amdgcn_mfma_f32_16x16x32_bf16(
            af[mt], bfr[nt], acc[mt][nt], 0, 0, 0);
  }
}

// ---------------- L1: q-proj (48) + Wk transpose (576) + search cvt ----------
__global__ __launch_bounds__(256) void k_pre(
    const float* __restrict__ query, const float* __restrict__ Wq,
    const float* __restrict__ bq, const float* __restrict__ W1,
    const float* __restrict__ Wk, const float* __restrict__ search,
    float* __restrict__ qf, unsigned short* __restrict__ QW,
    unsigned short* __restrict__ WkT, unsigned short* __restrict__ sb,
    int use_sb)
{
  __shared__ unsigned short As[64 * 64];
  __shared__ unsigned short Bs[64 * 64];
  __shared__ unsigned short tile[32][33];
  const int bid = blockIdx.x, t = threadIdx.x;
  const int wave = t >> 6, lane = t & 63;
  if (bid < 48) {
    // q-proj 64x64 (R6-verified phaseB): qv = query@Wq^T + bq
    const int by = bid / 12, bx = bid % 12;
    const int m0 = by * 64, n0 = bx * 64;
    const int wr = wave >> 1, wc = wave & 1;
    const int quad = lane >> 4, l15 = lane & 15;
    const int rl = lane >> 3, cL = lane & 7, p = cL ^ rl;
    floatx4 acc[2][2];
#pragma unroll
    for (int i = 0; i < 2; i++)
#pragma unroll
      for (int j = 0; j < 2; j++) acc[i][j] = (floatx4){0.f, 0.f, 0.f, 0.f};
    for (int k0 = 0; k0 < 768; k0 += 64) {
#pragma unroll
      for (int tt = 0; tt < 2; tt++) {
        int r = wave * 16 + tt * 8 + rl;
        cvt_store8(query + (size_t)(m0 + r) * 768 + k0 + cL * 8, As + r * 64 + p * 8);
        cvt_store8(Wq + (size_t)(n0 + r) * 768 + k0 + cL * 8, Bs + r * 64 + p * 8);
      }
      __syncthreads();
#pragma unroll
      for (int ks = 0; ks < 2; ks++) {
        shortx8 af[2], bfr[2];
#pragma unroll
        for (int mt = 0; mt < 2; mt++) {
          int r = wr * 32 + mt * 16 + l15;
          int ch = (ks * 4 + quad) ^ (r & 7);
          af[mt] = *(const shortx8*)(As + r * 64 + ch * 8);
        }
#pragma unroll
        for (int nt = 0; nt < 2; nt++) {
          int r = wc * 32 + nt * 16 + l15;
          int ch = (ks * 4 + quad) ^ (r & 7);
          bfr[nt] = *(const shortx8*)(Bs + r * 64 + ch * 8);
        }
#pragma unroll
        for (int mt = 0; mt < 2; mt++)
#pragma unroll
          for (int nt = 0; nt < 2; nt++)
            acc[mt][nt] = __builtin_amdgcn_mfma_f32_16x16x32_bf16(
                af[mt], bfr[nt], acc[mt][nt], 0, 0, 0);
      }
      __syncthreads();
    }
    const int lrow = quad * 4;
#pragma unroll
    for (int mt = 0; mt < 2; mt++)
#pragma unroll
      for (int nt = 0; nt < 2; nt++) {
        int gm = m0 + wr * 32 + mt * 16 + lrow;
        int gn = n0 + wc * 32 + nt * 16 + l15;
        float bz = bq[gn];
        int h = gn / 96;
        float w1h0 = W1[h], w1h1 = W1[8 + h], w1h2 = W1[16 + h], w1h3 = W1[24 + h];
#pragma unroll
        for (int r = 0; r < 4; r++) {
          float qv = acc[mt][nt][r] + bz;
          qf[(size_t)(gm + r) * 768 + gn] = qv;
          size_t base = (size_t)((gm + r) * 4) * 768 + gn;
          QW[base]           = f2bf(SCALE * w1h0 * qv);
          QW[base + 768]     = f2bf(SCALE * w1h1 * qv);
          QW[base + 2 * 768] = f2bf(SCALE * w1h2 * qv);
          QW[base + 3 * 768] = f2bf(SCALE * w1h3 * qv);
        }
      }
  } else if (bid < 624) {
    // Wk transpose -> WkT bf16 (R6-verified)
    const int tb = bid - 48, bx = tb % 24, by = tb / 24;
    const int tx = t & 31, ty = t >> 5;
#pragma unroll
    for (int i = 0; i < 4; i++)
      tile[ty + i * 8][tx] = f2bf(Wk[(size_t)(by * 32 + ty + i * 8) * 768 + bx * 32 + tx]);
    __syncthreads();
#pragma unroll
    for (int i = 0; i < 4; i++)
      WkT[(size_t)(bx * 32 + ty + i * 8) * 768 + by * 32 + tx] = tile[tx][ty + i * 8];
  } else {
    // search fp32 -> bf16 flood (grid-stride over 6144 jobs, 1000 blocks)
    for (int it = bid - 624; it < 6144; it += 1000) {
      size_t i = (size_t)it * 2048 + t * 8;
      cvt_store8(search + i, sb + i);
    }
  }
}

// ---------------- L2: QQ GEMM 64x64 (192 blocks) + cp (4 blocks) -------------
__global__ __launch_bounds__(256) void k_mid(
    const unsigned short* __restrict__ QW, const unsigned short* __restrict__ WkT,
    unsigned short* __restrict__ QQ,
    const float* __restrict__ qf, const float* __restrict__ W1,
    const float* __restrict__ b1, const float* __restrict__ bk,
    float* __restrict__ cp)
{
  __shared__ unsigned short As[64 * 64];
  __shared__ unsigned short Bs[64 * 64];
  const int bid = blockIdx.x, t = threadIdx.x;
  const int wave = t >> 6, lane = t & 63;
  if (bid < 192) {
    // QQ = QW @ WkT^T; M=1024, N=768, K=768; 64x64 tiles, async bf16 staging
    const int by = bid / 12, bx = bid % 12;
    const int m0 = by * 64, n0 = bx * 64;
    const int wr = wave >> 1, wc = wave & 1;
    const int quad = lane >> 4, l15 = lane & 15;
    const int rl = lane >> 3, cl = (lane & 7) ^ rl;
    floatx4 acc[2][2];
#pragma unroll
    for (int i = 0; i < 2; i++)
#pragma unroll
      for (int j = 0; j < 2; j++) acc[i][j] = (floatx4){0.f, 0.f, 0.f, 0.f};
    for (int k0 = 0; k0 < 768; k0 += 64) {
#pragma unroll
      for (int tt = 0; tt < 2; tt++) {
        int rr = wave * 16 + tt * 8;
        async_ld16(QW + (size_t)(m0 + rr + rl) * 768 + k0 + cl * 8, As + rr * 64);
        async_ld16(WkT + (size_t)(n0 + rr + rl) * 768 + k0 + cl * 8, Bs + rr * 64);
      }
      __syncthreads();
#pragma unroll
      for (int ks = 0; ks < 2; ks++) {
        shortx8 af[2], bfr[2];
#pragma unroll
        for (int mt = 0; mt < 2; mt++) {
          int r = wr * 32 + mt * 16 + l15;
          int ch = (ks * 4 + quad) ^ (r & 7);
          af[mt] = *(const shortx8*)(As + r * 64 + ch * 8);
        }
#pragma unroll
        for (int nt = 0; nt < 2; nt++) {
          int r = wc * 32 + nt * 16 + l15;
          int ch = (ks * 4 + quad) ^ (r & 7);
          bfr[nt] = *(const shortx8*)(Bs + r * 64 + ch * 8);
        }
#pragma unroll
        for (int mt = 0; mt < 2; mt++)
#pragma unroll
          for (int nt = 0; nt < 2; nt++)
            acc[mt][nt] = __builtin_amdgcn_mfma_f32_16x16x32_bf16(
                af[mt], bfr[nt], acc[mt][nt], 0, 0, 0);
      }
      __syncthreads();
    }
    const int lrow = quad * 4;
#pragma unroll
    for (int mt = 0; mt < 2; mt++)
#pragma unroll
      for (int nt = 0; nt < 2; nt++) {
        int gm = m0 + wr * 32 + mt * 16 + lrow;
        int gn = n0 + wc * 32 + nt * 16 + l15;
#pragma unroll
        for (int r = 0; r < 4; r++)
          QQ[(size_t)(gm + r) * 768 + gn] = f2bf(acc[mt][nt][r]);
      }
  } else {
    // cp[b*4+j] = b1[j] + SCALE * sum_h W1[j,h] * dot(qf[b,h*96:],bk[h*96:])
    const int bstart = (bid - 192) * 64;
    for (int b = bstart + wave; b < bstart + 64; b += 4) {
      const float* qrow = qf + (size_t)b * 768;
      int e0 = lane * 12;
      float s = 0.f;
#pragma unroll
      for (int i = 0; i < 12; i++) s += qrow[e0 + i] * bk[e0 + i];
      s += __shfl_xor(s, 1); s += __shfl_xor(s, 2); s += __shfl_xor(s, 4);
      float v = __shfl(s, (lane & 7) * 8);
      float w = W1[((lane >> 3) & 3) * 8 + (lane & 7)] * v;
      w += __shfl_xor(w, 1); w += __shfl_xor(w, 2); w += __shfl_xor(w, 4);
      if (lane < 32 && (lane & 7) == 0) {
        int j = lane >> 3;
        cp[b * 4 + j] = b1[j] + SCALE * w;
      }
    }
  }
}

// ---------------- L3: main GEMM + fused MLP epilogue (R6-verified phaseD) ----
__global__ __launch_bounds__(256) void k_main(
    const unsigned short* __restrict__ QQ, const void* __restrict__ Bv,
    float* __restrict__ out, const float* __restrict__ cp,
    const float* __restrict__ W2, const float* __restrict__ b2, int use_sb)
{
  __shared__ unsigned short As[128 * 64];
  __shared__ unsigned short Bs[128 * 64];
  const int bid = blockIdx.x;
  const int n_tile = (bid & 7) * 16 + ((bid >> 3) & 15);  // XCD swizzle
  const int m_tile = bid >> 7;
  const int m0 = m_tile * 128, n0 = n_tile * 128;
  const int t = threadIdx.x, wave = t >> 6, lane = t & 63;
  const int wr = wave >> 1, wc = wave & 1;
  const int quad = lane >> 4, l15 = lane & 15;
  floatx4 acc[4][4];
#pragma unroll
  for (int i = 0; i < 4; i++)
#pragma unroll
    for (int j = 0; j < 4; j++) acc[i][j] = (floatx4){0.f, 0.f, 0.f, 0.f};
  const int rl = lane >> 3, cl = (lane & 7) ^ rl, cL = lane & 7, p = cL ^ rl;
  for (int k0 = 0; k0 < 768; k0 += 64) {
#pragma unroll
    for (int tt = 0; tt < 4; tt++) {
      int rr = wave * 32 + tt * 8;
      async_ld16(QQ + (size_t)(m0 + rr + rl) * 768 + k0 + cl * 8, As + rr * 64);
    }
    if (use_sb) {
      const unsigned short* B16 = (const unsigned short*)Bv;
#pragma unroll
      for (int tt = 0; tt < 4; tt++) {
        int rr = wave * 32 + tt * 8;
        async_ld16(B16 + (size_t)(n0 + rr + rl) * 768 + k0 + cl * 8, Bs + rr * 64);
      }
    } else {
      const float* Bf = (const float*)Bv;
#pragma unroll
      for (int tt = 0; tt < 4; tt++) {
        int r = wave * 32 + tt * 8 + rl;
        cvt_store8(Bf + (size_t)(n0 + r) * 768 + k0 + cL * 8, Bs + r * 64 + p * 8);
      }
    }
    __syncthreads();
    mfma_consume(As, Bs, wr, wc, quad, l15, acc);
    __syncthreads();
  }
  const float w2v0 = W2[0], w2v1 = W2[1], w2v2 = W2[2], w2v3 = W2[3];
  const float b2v = b2[0];
  const int lrow = quad * 4;
#pragma unroll
  for (int mt = 0; mt < 4; mt++) {
    int gm = m0 + wr * 64 + mt * 16 + lrow;  // multiple of 4: rows gm..gm+3 = j 0..3
    float cpv0 = cp[gm], cpv1 = cp[gm + 1], cpv2 = cp[gm + 2], cpv3 = cp[gm + 3];
#pragma unroll
    for (int nt = 0; nt < 4; nt++) {
      int gn = n0 + wc * 64 + nt * 16 + l15;
      floatx4 v = acc[mt][nt];
      float s = b2v;
      s += w2v0 * gelu_fast(v[0] + cpv0);
      s += w2v1 * gelu_fast(v[1] + cpv1);
      s += w2v2 * gelu_fast(v[2] + cpv2);
      s += w2v3 * gelu_fast(v[3] + cpv3);
      out[(size_t)(gm >> 2) * 16384 + gn] = s;
    }
  }
}

extern "C" void kernel_launch(void* const* d_in, const int* in_sizes, int n_in,
                              void* d_out, int out_size, void* d_ws, size_t ws_size,
                              hipStream_t stream) {
  const float* query  = (const float*)d_in[0];
  const float* search = (const float*)d_in[1];
  const float* Wq     = (const float*)d_in[2];
  const float* bq     = (const float*)d_in[3];
  const float* Wk     = (const float*)d_in[4];
  const float* bk     = (const float*)d_in[5];
  const float* W1     = (const float*)d_in[6];
  const float* b1     = (const float*)d_in[7];
  const float* W2     = (const float*)d_in[8];
  const float* b2     = (const float*)d_in[9];
  float* out = (float*)d_out;

  char* ws = (char*)d_ws;
  float*          cp  = (float*)ws;                       //     4,096 B
  float*          qf  = (float*)(ws + 4352);              //   786,432 B
  unsigned short* WkT = (unsigned short*)(ws + 790784);   // 1,179,648 B
  unsigned short* QW  = (unsigned short*)(ws + 1970432);  // 1,572,864 B
  unsigned short* QQ  = (unsigned short*)(ws + 3543296);  // 1,572,864 B
  unsigned short* sb  = (unsigned short*)(ws + 5116160);  // 25,165,824 B -> 30,281,984
  int use_sb = (ws_size >= 30281984u) ? 1 : 0;

  // L1: q-proj + Wk transpose + search convert
  k_pre<<<use_sb ? 1624 : 624, 256, 0, stream>>>(query, Wq, bq, W1, Wk, search,
                                                 qf, QW, WkT, sb, use_sb);
  // L2: QQ GEMM + cp
  k_mid<<<196, 256, 0, stream>>>(QW, WkT, QQ, qf, W1, b1, bk, cp);
  // L3: main GEMM with fused MLP epilogue
  k_main<<<1024, 256, 0, stream>>>(QQ, use_sb ? (const void*)sb : (const void*)search,
                                   out, cp, W2, b2, use_sb);
}